// Round 5
// baseline (529.019 us; speedup 1.0000x reference)
//
#include <hip/hip_runtime.h>
#include <hip/hip_bf16.h>

// ---------- common helpers ----------
typedef __attribute__((ext_vector_type(8))) short short8;
typedef __attribute__((ext_vector_type(4))) float floatx4;

__device__ __forceinline__ ushort f2bf(float x) {
    unsigned u = __float_as_uint(x);
    unsigned r = (u + 0x7fffu + ((u >> 16) & 1u)) >> 16;
    return (ushort)r;
}
__device__ __forceinline__ float bf2f(ushort h) {
    return __uint_as_float(((unsigned)h) << 16);
}
__device__ __forceinline__ float fast_sigmoid(float x) {
    return 1.0f / (1.0f + __expf(-x));
}
__device__ __forceinline__ float fast_tanh(float x) {
    x = fminf(fmaxf(x, -15.0f), 15.0f);
    float e = __expf(2.0f * x);
    return (e - 1.0f) / (e + 1.0f);
}
__device__ __forceinline__ void load_lds16(const void* g, void* l) {
    __builtin_amdgcn_global_load_lds(
        (__attribute__((address_space(1))) void*)(g),
        (__attribute__((address_space(3))) void*)(l),
        16, 0, 0);
}

// ---------- swizzled LDS tile: units of 8 rows x 64 cols (1 KB) ----------
// Conflict-free (verified r3/r4: SQ_LDS_BANK_CONFLICT = 0).
__device__ __forceinline__ short8 lds_read8(const ushort* buf, int R, int c_el) {
    const int idx = ((R >> 3) << 9) + ((R & 7) << 6) + ((((c_el >> 3) ^ (R & 7))) << 3);
    return *(const short8*)(buf + idx);
}
__device__ __forceinline__ void stage_unit(const ushort* grow0, int ld, ushort* lds_unit) {
    const int lane = threadIdx.x & 63;
    const int r = lane >> 3;
    const int c = (lane & 7) ^ r;
    load_lds16(grow0 + (size_t)r * ld + c * 8, lds_unit);
}

// ---------- fp32 -> bf16 conversion ----------
__global__ __launch_bounds__(256) void cvt_f32_bf16(const float* __restrict__ src,
                                                    ushort* __restrict__ dst, int n4) {
    int i = blockIdx.x * blockDim.x + threadIdx.x;
    if (i >= n4) return;
    const float4 v = ((const float4*)src)[i];
    ushort4 o;
    o.x = f2bf(v.x); o.y = f2bf(v.y); o.z = f2bf(v.z); o.w = f2bf(v.w);
    ((ushort4*)dst)[i] = o;
}

// ---------- counting sort of rows by cnt descending ----------
__global__ __launch_bounds__(256) void sort_by_cnt(const int* __restrict__ cnt,
                                                   int* __restrict__ perm,
                                                   int* __restrict__ inv,
                                                   int* __restrict__ nact) {
    __shared__ int h[9];
    __shared__ int cur[9];
    const int tid = threadIdx.x;
    if (tid < 9) h[tid] = 0;
    __syncthreads();
    for (int i = tid; i < 4096; i += 256) atomicAdd(&h[cnt[i]], 1);
    __syncthreads();
    if (tid == 0) {
        int off = 0;
        for (int c = 8; c >= 0; --c) { cur[c] = off; off += h[c]; }
        for (int t = 0; t < 8; ++t) {
            int n = 0;
            for (int c = t + 1; c <= 8; ++c) n += h[c];
            nact[t] = n;
        }
    }
    __syncthreads();
    for (int i = tid; i < 4096; i += 256) {
        const int c = cnt[i];
        const int p = atomicAdd(&cur[c], 1);
        perm[p] = i;
        inv[i] = p;
    }
}

// ---------- enc GEMM: BM=128, BN=256, A via dbuf LDS, B direct global->VGPR ----------
// Writes fp32 partials (split-K); grid (N/256, M/128, KSPLIT).
template <int KSPLIT>
__global__ __launch_bounds__(256, 2) void gemm_bigm(
    const ushort* __restrict__ A, int lda,
    const ushort* __restrict__ B, int ldb,
    float* __restrict__ Cf, int ldc, int K, size_t part_stride) {
    __shared__ __attribute__((aligned(16))) ushort sA[2][128 * 64];  // 16 KB x2

    const int tid = threadIdx.x;
    const int lane = tid & 63;
    const int w = tid >> 6;
    const int m0 = blockIdx.y * 128;
    const int n0 = blockIdx.x * 256;
    const int nl = lane & 15;
    const int wcol = (lane >> 4) * 8;

    const int Kper = K / KSPLIT;
    const int kbase = blockIdx.z * Kper;
    Cf += (size_t)blockIdx.z * part_stride;

    // A staging pointers (swizzle baked in): 4 units per wave
    const int r = lane >> 3;
    const int c = (lane & 7) ^ r;
    const ushort* ab[4];
#pragma unroll
    for (int u = 0; u < 4; ++u) {
        const int ua = w * 4 + u;
        ab[u] = A + (size_t)(m0 + ua * 8 + r) * lda + kbase + c * 8;
    }
    // B fragment pointers (direct global)
    const ushort* bp[4];
#pragma unroll
    for (int j = 0; j < 4; ++j)
        bp[j] = B + (size_t)(n0 + w * 64 + j * 16 + nl) * ldb + kbase + wcol;

    floatx4 acc[8][4] = {};

    // prologue: stage k-tile 0
#pragma unroll
    for (int u = 0; u < 4; ++u) load_lds16(ab[u], &sA[0][(w * 4 + u) * 512]);

    const int iters = Kper / 64;
    for (int it = 0; it < iters; ++it) {
        const int cur = it & 1;
        __syncthreads();  // drains staging of sA[cur] (issued one compute-phase ago)
        if (it + 1 < iters) {
            const int kn = (it + 1) * 64;
#pragma unroll
            for (int u = 0; u < 4; ++u) load_lds16(ab[u] + kn, &sA[cur ^ 1][(w * 4 + u) * 512]);
        }
        const int k0 = it * 64;
#pragma unroll
        for (int kk = 0; kk < 2; ++kk) {
            const int kc = k0 + kk * 32;
            short8 b[4];
#pragma unroll
            for (int j = 0; j < 4; ++j) b[j] = *(const short8*)(bp[j] + kc);
            const int cb = kk * 32 + wcol;
            short8 a[8];
#pragma unroll
            for (int i = 0; i < 8; ++i) a[i] = lds_read8(&sA[cur][0], i * 16 + nl, cb);
#pragma unroll
            for (int i = 0; i < 8; ++i)
#pragma unroll
                for (int j = 0; j < 4; ++j)
                    acc[i][j] = __builtin_amdgcn_mfma_f32_16x16x32_bf16(a[i], b[j], acc[i][j], 0, 0, 0);
        }
    }

    const int ml = (lane >> 4) * 4;
#pragma unroll
    for (int j = 0; j < 4; ++j) {
        const int n = n0 + w * 64 + j * 16 + nl;
#pragma unroll
        for (int i = 0; i < 8; ++i) {
            const int mbase = m0 + i * 16 + ml;
#pragma unroll
            for (int r4 = 0; r4 < 4; ++r4)
                Cf[(size_t)(mbase + r4) * ldc + n] = acc[i][j][r4];
        }
    }
}

// ---------- legacy GEMM (used for pol): BM=64, swizzled LDS ----------
// MODE 2: +bias, relu, store bf16 AND fp32; MAP: scatter C rows via row_map
template <int MODE, int BN, bool MAP>
__global__ __launch_bounds__(256, 2) void gemm64(
    const ushort* __restrict__ A, int lda,
    const ushort* __restrict__ B, int ldb,
    const float* __restrict__ bias,
    const int* __restrict__ row_map,
    ushort* __restrict__ Cb, float* __restrict__ Cf, int ldc, int K) {
    __shared__ __attribute__((aligned(16))) ushort sA[64 * 64];
    __shared__ __attribute__((aligned(16))) ushort sB[BN * 64];

    constexpr int NJ = (BN + 63) / 64;
    constexpr int UB = BN / 32;

    const int tid = threadIdx.x;
    const int lane = tid & 63;
    const int w = tid >> 6;
    const int m0 = blockIdx.y * 64;
    const int n0 = blockIdx.x * BN;
    const int wn = w * (16 * NJ);
    const int nl = lane & 15;

    floatx4 acc[4][NJ] = {};

    for (int k0 = 0; k0 < K; k0 += 64) {
#pragma unroll
        for (int u = 0; u < 2; ++u) {
            const int ua = w * 2 + u;
            stage_unit(A + (size_t)(m0 + ua * 8) * lda + k0, lda, &sA[ua * 512]);
        }
#pragma unroll
        for (int u = 0; u < UB; ++u) {
            const int ub = w * UB + u;
            stage_unit(B + (size_t)(n0 + ub * 8) * ldb + k0, ldb, &sB[ub * 512]);
        }
        __syncthreads();
#pragma unroll
        for (int kk = 0; kk < 2; ++kk) {
            const int cb = kk * 32 + (lane >> 4) * 8;
            short8 a[4], b[NJ];
#pragma unroll
            for (int i = 0; i < 4; ++i) a[i] = lds_read8(sA, i * 16 + nl, cb);
#pragma unroll
            for (int j = 0; j < NJ; ++j) b[j] = lds_read8(sB, wn + j * 16 + nl, cb);
#pragma unroll
            for (int i = 0; i < 4; ++i)
#pragma unroll
                for (int j = 0; j < NJ; ++j)
                    acc[i][j] = __builtin_amdgcn_mfma_f32_16x16x32_bf16(a[i], b[j], acc[i][j], 0, 0, 0);
        }
        __syncthreads();
    }

    const int ml = (lane >> 4) * 4;
#pragma unroll
    for (int j = 0; j < NJ; ++j) {
        const int n = n0 + wn + j * 16 + nl;
        const float bv = bias[n];
#pragma unroll
        for (int i = 0; i < 4; ++i) {
            const int mbase = m0 + i * 16 + ml;
#pragma unroll
            for (int r = 0; r < 4; ++r) {
                float v = acc[i][j][r];
                const int mr = mbase + r;
                const int orow = MAP ? row_map[mr] : mr;
                const size_t off = (size_t)orow * ldc + n;
                v += bv; v = fmaxf(v, 0.0f);
                Cb[off] = f2bf(v);
                Cf[off] = v;
            }
        }
    }
}

// ---------- split-K combine: enc = relu(p0 + p1 + bias) -> bf16 ----------
__global__ __launch_bounds__(256) void combine_relu(const float* __restrict__ p0,
                                                    const float* __restrict__ p1,
                                                    const float* __restrict__ bias,
                                                    ushort* __restrict__ ob, int n4) {
    int i = blockIdx.x * blockDim.x + threadIdx.x;
    if (i >= n4) return;
    const float4 a = ((const float4*)p0)[i];
    const float4 b = ((const float4*)p1)[i];
    const int col = (i * 4) & 1023;
    const float4 bs = *(const float4*)(bias + col);
    ushort4 o;
    o.x = f2bf(fmaxf(a.x + b.x + bs.x, 0.f));
    o.y = f2bf(fmaxf(a.y + b.y + bs.y, 0.f));
    o.z = f2bf(fmaxf(a.z + b.z + bs.z, 0.f));
    o.w = f2bf(fmaxf(a.w + b.w + bs.w, 0.f));
    ((ushort4*)ob)[i] = o;
}

// ---------- fused GRU step, sorted row space ----------
// Block = 64 rows x 64 h-cols, all gates. X/H via double-buffered LDS (16 KB x2);
// weight fragments direct global->VGPR (per-wave-private cols, L2-hot).
__global__ __launch_bounds__(256, 2) void gru_step(
    const ushort* __restrict__ Xall,  // nbr_b (orig rows, stride 4096), +t*512
    const ushort* __restrict__ Hin,   // [4096,512] bf16, sorted space
    const ushort* __restrict__ Wih,   // [1536,512] bf16
    const ushort* __restrict__ Whh,   // [1536,512] bf16
    const float* __restrict__ bih, const float* __restrict__ bhh,
    const int* __restrict__ perm, const int* __restrict__ nact,
    float* __restrict__ hf, ushort* __restrict__ Hout, int t) {
    __shared__ __attribute__((aligned(16))) ushort sX[2][64 * 64];  // 8 KB x2
    __shared__ __attribute__((aligned(16))) ushort sH[2][64 * 64];  // 8 KB x2

    const int tid = threadIdx.x;
    const int lane = tid & 63;
    const int w = tid >> 6;
    const int s = blockIdx.x;        // col slab 0..7
    const int m0 = blockIdx.y * 64;  // sorted batch-row base
    const int na = nact[t];

    if (m0 >= na) {
        // fully inactive: copy h slab forward (hf untouched)
        const int rr = tid >> 2;
        const size_t base = (size_t)(m0 + rr) * 512 + s * 64;
        const uint4* src = (const uint4*)(Hin + base);
        uint4* dst = (uint4*)(Hout + base);
        const int cc = (tid & 3) * 2;
        dst[cc] = src[cc];
        dst[cc + 1] = src[cc + 1];
        return;
    }

    const int nl = lane & 15;
    const int ml = (lane >> 4) * 4;
    const int wcol = (lane >> 4) * 8;
    const int col = s * 64 + w * 16 + nl;  // this lane's h column

    // staging pointers (swizzle + perm gather baked in)
    const int r = lane >> 3;
    const int c = (lane & 7) ^ r;
    const ushort* X = Xall + t * 512;
    const ushort* xb[2];
    const ushort* hbp[2];
#pragma unroll
    for (int u = 0; u < 2; ++u) {
        const int srow = m0 + (w * 2 + u) * 8 + r;
        xb[u] = X + (size_t)perm[srow] * 4096 + c * 8;
        hbp[u] = Hin + (size_t)srow * 512 + c * 8;
    }
    // direct weight fragment pointers (row = gate*512 + col, k-offset added in loop)
    const ushort* pir = Wih + (size_t)col * 512 + wcol;
    const ushort* piz = Wih + (size_t)(512 + col) * 512 + wcol;
    const ushort* pin = Wih + (size_t)(1024 + col) * 512 + wcol;
    const ushort* phr = Whh + (size_t)col * 512 + wcol;
    const ushort* phz = Whh + (size_t)(512 + col) * 512 + wcol;
    const ushort* phn = Whh + (size_t)(1024 + col) * 512 + wcol;

    // acc init with biases (depend only on column)
    floatx4 accr[4], accz[4], accn[4], acch[4];
    {
        const float br_ = bih[col] + bhh[col];
        const float bz_ = bih[512 + col] + bhh[512 + col];
        const float bni = bih[1024 + col];
        const float bnh = bhh[1024 + col];
        const floatx4 vr = {br_, br_, br_, br_};
        const floatx4 vz = {bz_, bz_, bz_, bz_};
        const floatx4 vi = {bni, bni, bni, bni};
        const floatx4 vh = {bnh, bnh, bnh, bnh};
#pragma unroll
        for (int i = 0; i < 4; ++i) { accr[i] = vr; accz[i] = vz; accn[i] = vi; acch[i] = vh; }
    }

    // prologue: stage k-tile 0
#pragma unroll
    for (int u = 0; u < 2; ++u) {
        const int ua = w * 2 + u;
        load_lds16(xb[u], &sX[0][ua * 512]);
        load_lds16(hbp[u], &sH[0][ua * 512]);
    }

    for (int it = 0; it < 8; ++it) {
        const int cur = it & 1;
        __syncthreads();  // sA[cur] staging had a full compute phase to land
        if (it < 7) {
            const int kn = (it + 1) * 64;
#pragma unroll
            for (int u = 0; u < 2; ++u) {
                const int ua = w * 2 + u;
                load_lds16(xb[u] + kn, &sX[cur ^ 1][ua * 512]);
                load_lds16(hbp[u] + kn, &sH[cur ^ 1][ua * 512]);
            }
        }
        const int k0 = it * 64;
        // issue all 12 weight-frag loads for this k-tile up front (L2-hot)
        short8 wf[12];
#pragma unroll
        for (int kk = 0; kk < 2; ++kk) {
            const int kc = k0 + kk * 32;
            wf[kk * 6 + 0] = *(const short8*)(pir + kc);
            wf[kk * 6 + 1] = *(const short8*)(piz + kc);
            wf[kk * 6 + 2] = *(const short8*)(pin + kc);
            wf[kk * 6 + 3] = *(const short8*)(phr + kc);
            wf[kk * 6 + 4] = *(const short8*)(phz + kc);
            wf[kk * 6 + 5] = *(const short8*)(phn + kc);
        }
#pragma unroll
        for (int kk = 0; kk < 2; ++kk) {
            const int cb = kk * 32 + wcol;
            short8 ax[4], ah[4];
#pragma unroll
            for (int i = 0; i < 4; ++i) {
                ax[i] = lds_read8(&sX[cur][0], i * 16 + nl, cb);
                ah[i] = lds_read8(&sH[cur][0], i * 16 + nl, cb);
            }
#pragma unroll
            for (int i = 0; i < 4; ++i) {
                accr[i] = __builtin_amdgcn_mfma_f32_16x16x32_bf16(ax[i], wf[kk * 6 + 0], accr[i], 0, 0, 0);
                accr[i] = __builtin_amdgcn_mfma_f32_16x16x32_bf16(ah[i], wf[kk * 6 + 3], accr[i], 0, 0, 0);
                accz[i] = __builtin_amdgcn_mfma_f32_16x16x32_bf16(ax[i], wf[kk * 6 + 1], accz[i], 0, 0, 0);
                accz[i] = __builtin_amdgcn_mfma_f32_16x16x32_bf16(ah[i], wf[kk * 6 + 4], accz[i], 0, 0, 0);
                accn[i] = __builtin_amdgcn_mfma_f32_16x16x32_bf16(ax[i], wf[kk * 6 + 2], accn[i], 0, 0, 0);
                acch[i] = __builtin_amdgcn_mfma_f32_16x16x32_bf16(ah[i], wf[kk * 6 + 5], acch[i], 0, 0, 0);
            }
        }
    }

    // epilogue: gates + positional mask
    const bool full = (m0 + 64 <= na);
#pragma unroll
    for (int i = 0; i < 4; ++i) {
#pragma unroll
        for (int r4 = 0; r4 < 4; ++r4) {
            const int row = m0 + i * 16 + ml + r4;
            const float rg = fast_sigmoid(accr[i][r4]);
            const float zg = fast_sigmoid(accz[i][r4]);
            const float ng = fast_tanh(accn[i][r4] + rg * acch[i][r4]);
            const size_t off = (size_t)row * 512 + col;
            const float ho = hf[off];
            const bool act = full || (row < na);
            const float hv = act ? ((1.0f - zg) * ng + zg * ho) : ho;
            hf[off] = hv;
            Hout[off] = f2bf(hv);
        }
    }
}

// ---------- v_net: tanh(enc @ W_v^T + b_v), one wave per row ----------
__global__ __launch_bounds__(256) void v_kernel(const ushort* __restrict__ enc,
                                                const float* __restrict__ Wv,
                                                const float* __restrict__ bv,
                                                float* __restrict__ out) {
    const int row = blockIdx.x * 4 + (threadIdx.x >> 6);
    const int lane = threadIdx.x & 63;
    const ushort* e = enc + (size_t)row * 1024;
    float s = 0.0f;
#pragma unroll
    for (int i = 0; i < 16; ++i) {
        int k = lane + i * 64;
        s += bf2f(e[k]) * Wv[k];
    }
#pragma unroll
    for (int off = 32; off; off >>= 1) s += __shfl_down(s, off, 64);
    if (lane == 0) out[row] = fast_tanh(s + bv[0]);
}

// ---------- to_probs: softmax(relu(h @ W_pr^T + b_pr)); sorted -> orig scatter ----------
__global__ __launch_bounds__(256) void probs_kernel(const float* __restrict__ h,
                                                    const float* __restrict__ Wpr,
                                                    const float* __restrict__ bpr,
                                                    const int* __restrict__ perm,
                                                    float* __restrict__ out) {
    const int srow = blockIdx.x * 4 + (threadIdx.x >> 6);
    const int lane = threadIdx.x & 63;
    const float* hr = h + (size_t)srow * 512;
    float p0 = 0.f, p1 = 0.f, p2 = 0.f;
#pragma unroll
    for (int i = 0; i < 8; ++i) {
        int k = lane + i * 64;
        float x = hr[k];
        p0 += x * Wpr[k];
        p1 += x * Wpr[512 + k];
        p2 += x * Wpr[1024 + k];
    }
#pragma unroll
    for (int off = 32; off; off >>= 1) {
        p0 += __shfl_down(p0, off, 64);
        p1 += __shfl_down(p1, off, 64);
        p2 += __shfl_down(p2, off, 64);
    }
    if (lane == 0) {
        const int orow = perm[srow];
        p0 = fmaxf(p0 + bpr[0], 0.f);
        p1 = fmaxf(p1 + bpr[1], 0.f);
        p2 = fmaxf(p2 + bpr[2], 0.f);
        float m = fmaxf(p0, fmaxf(p1, p2));
        float e0 = __expf(p0 - m), e1 = __expf(p1 - m), e2 = __expf(p2 - m);
        float inv = 1.0f / (e0 + e1 + e2);
        out[orow * 3 + 0] = e0 * inv;
        out[orow * 3 + 1] = e1 * inv;
        out[orow * 3 + 2] = e2 * inv;
    }
}

extern "C" void kernel_launch(void* const* d_in, const int* in_sizes, int n_in,
                              void* d_out, int out_size, void* d_ws, size_t ws_size,
                              hipStream_t stream) {
    const float* obs   = (const float*)d_in[0];
    const float* nbr   = (const float*)d_in[1];
    const int*   cnt   = (const int*)d_in[2];
    const float* W_ds  = (const float*)d_in[3];
    const float* b_ds  = (const float*)d_in[4];
    const float* W_pol = (const float*)d_in[5];
    const float* b_pol = (const float*)d_in[6];
    const float* W_v   = (const float*)d_in[7];
    const float* b_v   = (const float*)d_in[8];
    const float* W_ih  = (const float*)d_in[9];
    const float* b_ih  = (const float*)d_in[10];
    const float* W_hh  = (const float*)d_in[11];
    const float* b_hh  = (const float*)d_in[12];
    const float* W_pr  = (const float*)d_in[13];
    const float* b_pr  = (const float*)d_in[14];
    float* out = (float*)d_out;  // [4096*3 probs][4096 state_vals]

    // workspace layout
    ushort* obs_b  = (ushort*)d_ws;              // 32 MB
    ushort* Wds_b  = obs_b + 16777216;           // 8 MB
    ushort* Wpol_b = Wds_b + 4194304;            // 1 MB
    ushort* Wih_b  = Wpol_b + 524288;            // 1.5 MB
    ushort* Whh_b  = Wih_b + 786432;             // 1.5 MB
    ushort* enc_b  = Whh_b + 786432;             // 8 MB
    ushort* h_b0   = enc_b + 4194304;            // 4 MB
    ushort* h_b1   = h_b0 + 2097152;             // 4 MB
    float*  h_f    = (float*)(h_b1 + 2097152);   // 8 MB
    float*  part   = h_f + 2097152;              // 32 MB (2 x 16 MB partials)
    ushort* nbr_b  = (ushort*)part;              // 32 MB, reuses part AFTER combine
    int*    perm   = (int*)(part + 8388608);
    int*    inv    = perm + 4096;
    int*    nact   = inv + 4096;
    // total ~100 MB + 32 KB

    // 0) sort rows by neighbor count (descending)
    sort_by_cnt<<<1, 256, 0, stream>>>(cnt, perm, inv, nact);

    // 1) convert obs + weights to bf16
    cvt_f32_bf16<<<16384, 256, 0, stream>>>(obs, obs_b, 4194304);
    cvt_f32_bf16<<<4096, 256, 0, stream>>>(W_ds, Wds_b, 1048576);
    cvt_f32_bf16<<<512, 256, 0, stream>>>(W_pol, Wpol_b, 131072);
    cvt_f32_bf16<<<768, 256, 0, stream>>>(W_ih, Wih_b, 196608);
    cvt_f32_bf16<<<768, 256, 0, stream>>>(W_hh, Whh_b, 196608);

    // 2) enc = relu(obs @ W_ds^T + b_ds): BM=128/BN=256, split-K=2, B direct
    gemm_bigm<2><<<dim3(4, 32, 2), 256, 0, stream>>>(
        obs_b, 4096, Wds_b, 4096, part, 1024, 4096, 4194304);
    combine_relu<<<4096, 256, 0, stream>>>(part, part + 4194304, b_ds, enc_b, 1048576);

    // 3) nbr -> bf16 into the (now free) split-K scratch
    cvt_f32_bf16<<<16384, 256, 0, stream>>>(nbr, nbr_b, 4194304);

    // 4) pol = relu(enc @ W_pol^T + b_pol) scattered into sorted space
    gemm64<2, 64, true><<<dim3(8, 64), 256, 0, stream>>>(
        enc_b, 1024, Wpol_b, 1024, b_pol, inv, h_b0, h_f, 512, 1024);

    // 5) state_vals (original space)
    v_kernel<<<1024, 256, 0, stream>>>(enc_b, W_v, b_v, out + 12288);

    // 6) GRU: 8 fused steps, weights direct from L2, X/H dbuf LDS
    for (int t = 0; t < 8; ++t) {
        const ushort* hin = (t & 1) ? h_b1 : h_b0;
        ushort* hout = (t & 1) ? h_b0 : h_b1;
        gru_step<<<dim3(8, 64), 256, 0, stream>>>(nbr_b, hin, Wih_b, Whh_b,
                                                  b_ih, b_hh, perm, nact, h_f, hout, t);
    }

    // 7) probs (sorted -> original scatter)
    probs_kernel<<<1024, 256, 0, stream>>>(h_f, W_pr, b_pr, perm, out);
}